// Round 1
// baseline (421.209 us; speedup 1.0000x reference)
//
#include <hip/hip_runtime.h>

// out[b,s,e] = prod_{j<=e} cos(x[b,s,j])  -- cumprod of cos along last axis.
// x: f32[16, 8192, 512]  ->  rows = 16*8192 = 131072 rows of length 512.
// One 64-lane wave per row: each lane owns 8 contiguous elements (2x float4),
// lane-local prefix products, then a 6-step shfl_up exclusive scan across the
// wave, then scale + 2x float4 store. Memory-bound: 512 MiB total traffic.

#define ROW_LEN 512
#define ELEMS_PER_LANE 8  // 512 / 64

__global__ __launch_bounds__(256) void cumprod_cos_kernel(
    const float* __restrict__ x, float* __restrict__ out, int nrows) {
    const int wave_in_block = threadIdx.x >> 6;
    const int lane          = threadIdx.x & 63;
    const int row = blockIdx.x * (blockDim.x >> 6) + wave_in_block;
    if (row >= nrows) return;

    const size_t row_base = (size_t)row * ROW_LEN;
    // lane's chunk: elements [lane*8, lane*8+8)
    const float4* __restrict__ xin =
        reinterpret_cast<const float4*>(x + row_base) + lane * 2;
    float4 a = xin[0];
    float4 b = xin[1];

    // cos of the 8 local elements
    float c0 = __cosf(a.x) , c1 = __cosf(a.y), c2 = __cosf(a.z), c3 = __cosf(a.w);
    float c4 = __cosf(b.x) , c5 = __cosf(b.y), c6 = __cosf(b.z), c7 = __cosf(b.w);
    // use precise cosf instead if accuracy is marginal; start precise:
    c0 = cosf(a.x); c1 = cosf(a.y); c2 = cosf(a.z); c3 = cosf(a.w);
    c4 = cosf(b.x); c5 = cosf(b.y); c6 = cosf(b.z); c7 = cosf(b.w);

    // lane-local inclusive prefix products
    float p0 = c0;
    float p1 = p0 * c1;
    float p2 = p1 * c2;
    float p3 = p2 * c3;
    float p4 = p3 * c4;
    float p5 = p4 * c5;
    float p6 = p5 * c6;
    float p7 = p6 * c7;

    // wave-wide inclusive scan (product) of lane totals, 6 butterfly-up steps
    float scan = p7;
    #pragma unroll
    for (int off = 1; off < 64; off <<= 1) {
        float n = __shfl_up(scan, off, 64);
        scan *= (lane >= off) ? n : 1.0f;
    }
    // exclusive prefix for this lane
    float excl = __shfl_up(scan, 1, 64);
    if (lane == 0) excl = 1.0f;

    float4 o0 = make_float4(excl * p0, excl * p1, excl * p2, excl * p3);
    float4 o1 = make_float4(excl * p4, excl * p5, excl * p6, excl * p7);
    float4* __restrict__ op = reinterpret_cast<float4*>(out + row_base) + lane * 2;
    op[0] = o0;
    op[1] = o1;
}

extern "C" void kernel_launch(void* const* d_in, const int* in_sizes, int n_in,
                              void* d_out, int out_size, void* d_ws, size_t ws_size,
                              hipStream_t stream) {
    const float* x = (const float*)d_in[0];
    float* out = (float*)d_out;
    const int nrows = in_sizes[0] / ROW_LEN;  // 131072
    const int waves_per_block = 4;            // 256 threads
    const int grid = (nrows + waves_per_block - 1) / waves_per_block;
    cumprod_cos_kernel<<<grid, 256, 0, stream>>>(x, out, nrows);
}